// Round 4
// baseline (639.675 us; speedup 1.0000x reference)
//
#include <hip/hip_runtime.h>
#include <stdint.h>
#include <stddef.h>

typedef __bf16 bf16_t;
typedef __bf16 bf16x8 __attribute__((ext_vector_type(8)));
typedef __bf16 bf16x4 __attribute__((ext_vector_type(4)));
typedef __bf16 bf16x2 __attribute__((ext_vector_type(2)));
typedef float  f32x4  __attribute__((ext_vector_type(4)));

#define SEQ   3072
#define DIMD  2048
#define NH    16
#define HD    128
#define QKVN  6144

__device__ __forceinline__ void async16(const bf16_t* g, bf16_t* l) {
  __builtin_amdgcn_global_load_lds((const __attribute__((address_space(1))) uint32_t*)g,
                                   (__attribute__((address_space(3))) uint32_t*)l, 16, 0, 0);
}

// ---------------- fused converts + bias pack (one launch) ----------------
__global__ __launch_bounds__(256) void cvt_all(const float* __restrict__ x,
                                               const float* __restrict__ Wq,
                                               const float* __restrict__ Wk,
                                               const float* __restrict__ Wv,
                                               const float* __restrict__ Wo,
                                               const float* __restrict__ bq,
                                               const float* __restrict__ bk,
                                               const float* __restrict__ bv,
                                               bf16_t* __restrict__ xb,
                                               bf16_t* __restrict__ Wqkvb,
                                               bf16_t* __restrict__ Wob,
                                               float* __restrict__ bqkv) {
  const int b = blockIdx.x;
  const float* src; bf16_t* dst; int off;
  if (b < 3072)       { src = x;  dst = xb;              off = b; }
  else if (b < 5120)  { src = Wq; dst = Wqkvb;           off = b - 3072; }
  else if (b < 7168)  { src = Wk; dst = Wqkvb + 4194304; off = b - 5120; }
  else if (b < 9216)  { src = Wv; dst = Wqkvb + 8388608; off = b - 7168; }
  else if (b < 11264) { src = Wo; dst = Wob;             off = b - 9216; }
  else {  // bias pack: 24 blocks cover 6144
    int t = (b - 11264) * 256 + threadIdx.x;
    float v;
    if (t < 2048)      v = bq[t];
    else if (t < 4096) v = bk[t - 2048];
    else               v = bv[t - 4096];
    bqkv[t] = v;
    return;
  }
  const int idx = (off * 256 + threadIdx.x) * 8;
  const float4 a = *(const float4*)(src + idx);
  const float4 c = *(const float4*)(src + idx + 4);
  bf16x8 o;
  o[0] = (bf16_t)a.x; o[1] = (bf16_t)a.y; o[2] = (bf16_t)a.z; o[3] = (bf16_t)a.w;
  o[4] = (bf16_t)c.x; o[5] = (bf16_t)c.y; o[6] = (bf16_t)c.z; o[7] = (bf16_t)c.w;
  *(bf16x8*)(dst + idx) = o;
}

// ---------------- GEMM: C[M,N] = A[M,K] * B[N,K]^T + bias ----------------
template<bool OUT_BF16>
__global__ __launch_bounds__(256, 2) void gemm_nt(const bf16_t* __restrict__ A,
                                                  const bf16_t* __restrict__ B,
                                                  const float* __restrict__ bias,
                                                  void* __restrict__ Cout,
                                                  int M, int N, int K) {
  __shared__ __align__(16) bf16_t As[128 * 64];
  __shared__ __align__(16) bf16_t Bs[128 * 64];
  const int t = threadIdx.x;
  const int lane = t & 63, wave = t >> 6;
  const int quad = lane >> 4, l15 = lane & 15;
  const int wy = wave >> 1, wx = wave & 1;
  const size_t bm = (size_t)blockIdx.y * 128, bn = (size_t)blockIdx.x * 128;
  const bf16_t* Ab = A + bm * K;
  const bf16_t* Bb = B + bn * K;
  f32x4 acc[4][4] = {};
  int srow[4], scol[4];
#pragma unroll
  for (int r = 0; r < 4; r++) {
    int L = r * 256 + t;
    int row = L >> 3, cp = L & 7;
    srow[r] = row;
    scol[r] = (cp ^ (row & 7)) * 8;
  }
  for (int k0 = 0; k0 < K; k0 += 64) {
    __syncthreads();
#pragma unroll
    for (int r = 0; r < 4; r++)
      async16(Ab + (size_t)srow[r] * K + k0 + scol[r], &As[(r * 256 + t) * 8]);
#pragma unroll
    for (int r = 0; r < 4; r++)
      async16(Bb + (size_t)srow[r] * K + k0 + scol[r], &Bs[(r * 256 + t) * 8]);
    __syncthreads();
#pragma unroll
    for (int ks = 0; ks < 2; ks++) {
      bf16x8 af[4], bfv[4];
#pragma unroll
      for (int i = 0; i < 4; i++) {
        int row = wy * 64 + i * 16 + l15;
        af[i] = *(const bf16x8*)&As[row * 64 + (((ks * 4 + quad) ^ (row & 7)) * 8)];
      }
#pragma unroll
      for (int j = 0; j < 4; j++) {
        int row = wx * 64 + j * 16 + l15;
        bfv[j] = *(const bf16x8*)&Bs[row * 64 + (((ks * 4 + quad) ^ (row & 7)) * 8)];
      }
#pragma unroll
      for (int i = 0; i < 4; i++)
#pragma unroll
        for (int j = 0; j < 4; j++)
          acc[i][j] = __builtin_amdgcn_mfma_f32_16x16x32_bf16(af[i], bfv[j], acc[i][j], 0, 0, 0);
    }
  }
#pragma unroll
  for (int i = 0; i < 4; i++) {
#pragma unroll
    for (int j = 0; j < 4; j++) {
      size_t row = bm + wy * 64 + i * 16 + quad * 4;
      size_t col = bn + wx * 64 + j * 16 + l15;
      float bb = bias[col];
#pragma unroll
      for (int r = 0; r < 4; r++) {
        float v = acc[i][j][r] + bb;
        if (OUT_BF16) ((bf16_t*)Cout)[(row + r) * N + col] = (bf16_t)v;
        else          ((float*)Cout)[(row + r) * N + col] = v;
      }
    }
  }
}

// ---------------- RMS + RoPE; q in-place, k packed to pk[h][s][d] ----------------
__global__ __launch_bounds__(256) void rmsrope(bf16_t* __restrict__ qkv,
                                               bf16_t* __restrict__ pk,
                                               const float* __restrict__ gq,
                                               const float* __restrict__ gk,
                                               const float* __restrict__ freqs) {
  const int s = blockIdx.x, t = threadIdx.x;
  bf16_t* row = qkv + (size_t)s * QKVN;
  bf16x8 qv = *(const bf16x8*)&row[t * 8];
  bf16x8 kv = *(const bf16x8*)&row[2048 + t * 8];
  float qf[8], kf[8];
  float qs = 0.f, ks2 = 0.f;
#pragma unroll
  for (int i = 0; i < 8; i++) {
    qf[i] = (float)qv[i]; qs  += qf[i] * qf[i];
    kf[i] = (float)kv[i]; ks2 += kf[i] * kf[i];
  }
#pragma unroll
  for (int m = 1; m < 64; m <<= 1) {
    qs  += __shfl_xor(qs, m);
    ks2 += __shfl_xor(ks2, m);
  }
  __shared__ float red[2][4];
  const int wave = t >> 6, lane = t & 63;
  if (lane == 0) { red[0][wave] = qs; red[1][wave] = ks2; }
  __syncthreads();
  qs  = red[0][0] + red[0][1] + red[0][2] + red[0][3];
  ks2 = red[1][0] + red[1][1] + red[1][2] + red[1][3];
  const float qsc = rsqrtf(qs  / 2048.f + 1e-6f);
  const float ksc = rsqrtf(ks2 / 2048.f + 1e-6f);
  const int sf = s / 384, rem = s - sf * 384;
  const int sh = rem / 24, sw = rem - sh * 24;
  bf16x8 qo, ko;
#pragma unroll
  for (int u = 0; u < 4; u++) {
    const int col = t * 8 + 2 * u;
    const int i = (col >> 1) & 63;                         // pair index within head (c=64)
    const int frow = (i < 22) ? sf : ((i < 43) ? sh : sw); // cf=22, ch=cw=21
    const float ang = freqs[frow * 64 + i];
    float sn, cs;
    __sincosf(ang, &sn, &cs);
    float te = qf[2 * u]     * qsc * gq[col];
    float to = qf[2 * u + 1] * qsc * gq[col + 1];
    qo[2 * u]     = (bf16_t)(te * cs - to * sn);
    qo[2 * u + 1] = (bf16_t)(te * sn + to * cs);
    te = kf[2 * u]     * ksc * gk[col];
    to = kf[2 * u + 1] * ksc * gk[col + 1];
    ko[2 * u]     = (bf16_t)(te * cs - to * sn);
    ko[2 * u + 1] = (bf16_t)(te * sn + to * cs);
  }
  *(bf16x8*)&row[t * 8] = qo;
  // packed K: pk[h][s][d], h = t>>4, d = (t&15)*8
  *(bf16x8*)&pk[((size_t)(t >> 4) * SEQ + s) * HD + (t & 15) * 8] = ko;
}

// ---------------- V transpose: pvt[h][d][s] = qkv[s][4096 + h*128 + d] ----------------
__global__ __launch_bounds__(256) void vtrans(const bf16_t* __restrict__ qkv,
                                              bf16_t* __restrict__ pvt) {
  __shared__ bf16_t tile[128][65];
  const int h = blockIdx.y;
  const int s0 = blockIdx.x * 64;
  const int t = threadIdx.x;
#pragma unroll
  for (int r = 0; r < 4; r++) {
    int L = r * 256 + t, s = L >> 4, cp = L & 15;
    bf16x8 v = *(const bf16x8*)&qkv[(size_t)(s0 + s) * QKVN + 4096 + h * HD + cp * 8];
#pragma unroll
    for (int i = 0; i < 8; i++) tile[cp * 8 + i][s] = v[i];
  }
  __syncthreads();
#pragma unroll
  for (int r = 0; r < 4; r++) {
    int L = r * 256 + t, d = L >> 3, c = L & 7;
    bf16x8 o;
#pragma unroll
    for (int i = 0; i < 8; i++) o[i] = tile[d][c * 8 + i];
    *(bf16x8*)&pvt[((size_t)h * HD + d) * SEQ + s0 + c * 8] = o;
  }
}

// ---------------- Flash attention: q-tile 256, 8 waves, KV-split 4 ----------------
// Grid 768 x 512 threads: bid -> xcd=bid&7; 8 streams/xcd (h,quarter), 12 q-tiles.
// Per wave: 32 q rows, identical inner structure to the proven 4-wave kernel.
// Partial O (normalized, bf16) per quarter: q0,q1 -> dead k/v cols of qkv;
// q2 -> scratch; q3 -> obuf. (m,l) -> mlbuf (parked in d_out, overwritten later).
__global__ __launch_bounds__(512, 4) void flash_attn(const bf16_t* __restrict__ qkv,
                                                     const bf16_t* __restrict__ pk,
                                                     const bf16_t* __restrict__ pvt,
                                                     bf16_t* __restrict__ qkvw,
                                                     bf16_t* __restrict__ oscr2,
                                                     bf16_t* __restrict__ oscr3,
                                                     float2* __restrict__ ml) {
  __shared__ __align__(16) bf16_t Ks[64 * 128];     // [kv][d], 16 chunks/row, xor-swizzled
  __shared__ __align__(16) bf16_t Vt[128 * 64];     // [d][kv], 8 chunks/row, xor-swizzled
  __shared__ __align__(16) bf16_t Ps[8][32 * 64];   // per-wave P [q][kv], swizzled
  const int bid = blockIdx.x;
  const int xcd = bid & 7, slot = bid >> 3;      // slot 0..95
  const int strm = slot & 7, qt = slot >> 3;     // 8 streams/xcd, 12 q-tiles
  const int sid = xcd * 8 + strm;                // 0..63
  const int h = sid & 15, quarter = sid >> 4;    // head, kv-quarter
  const int s0 = qt * 256;
  const int t = threadIdx.x, wave = t >> 6, lane = t & 63;
  const int quad = lane >> 4, l15 = lane & 15;
  const int wq = wave * 32;
  const float scale = 0.08838834764831845f;  // 1/sqrt(128)
  const bf16_t* pkh = pk  + (size_t)h * (SEQ * HD);
  const bf16_t* pvh = pvt + (size_t)h * (HD * SEQ);
  bf16x8 qfr[2][4];
#pragma unroll
  for (int tj = 0; tj < 2; tj++)
#pragma unroll
    for (int ks = 0; ks < 4; ks++)
      qfr[tj][ks] = *(const bf16x8*)&qkv[(size_t)(s0 + wq + tj * 16 + l15) * QKVN + h * HD + ks * 32 + quad * 8];
  f32x4 oacc[2][8] = {};
  float m_run[2] = {-3e38f, -3e38f}, l_run[2] = {0.f, 0.f};
  for (int kt = 0; kt < 12; kt++) {
    const int kv0 = (quarter * 12 + kt) * 64;
    __syncthreads();
    // stage K tile (64x128): 1024 16B chunks over 512 threads
#pragma unroll
    for (int r = 0; r < 2; r++) {
      int L = r * 512 + t, krow = L >> 4, cp = L & 15;
      int c = cp ^ (krow & 7);
      async16(pkh + (size_t)(kv0 + krow) * HD + c * 8, &Ks[L * 8]);
    }
    // stage V^T tile (128x64): 1024 16B chunks
#pragma unroll
    for (int r = 0; r < 2; r++) {
      int L = r * 512 + t, d = L >> 3, cp = L & 7;
      int c = cp ^ (d & 7);
      async16(pvh + (size_t)d * SEQ + kv0 + c * 8, &Vt[L * 8]);
    }
    __syncthreads();
    // S^T = K * Q^T  -> lane holds S^T[kv=ti*16+quad*4+r][q=tj*16+l15]
    f32x4 st[4][2] = {};
#pragma unroll
    for (int ks = 0; ks < 4; ks++) {
      bf16x8 kfr[4];
#pragma unroll
      for (int ti = 0; ti < 4; ti++) {
        const int kr = ti * 16 + l15;
        kfr[ti] = *(const bf16x8*)&Ks[kr * 128 + (((ks * 4 + quad) ^ (kr & 7)) * 8)];
      }
#pragma unroll
      for (int ti = 0; ti < 4; ti++)
#pragma unroll
        for (int tj = 0; tj < 2; tj++)
          st[ti][tj] = __builtin_amdgcn_mfma_f32_16x16x32_bf16(kfr[ti], qfr[tj][ks], st[ti][tj], 0, 0, 0);
    }
    // online softmax over kv (column reduction of S^T = across quads)
    float mt[2] = {-3e38f, -3e38f};
#pragma unroll
    for (int ti = 0; ti < 4; ti++)
#pragma unroll
      for (int tj = 0; tj < 2; tj++)
#pragma unroll
        for (int r = 0; r < 4; r++) {
          st[ti][tj][r] *= scale;
          mt[tj] = fmaxf(mt[tj], st[ti][tj][r]);
        }
    float al[2];
#pragma unroll
    for (int tj = 0; tj < 2; tj++) {
      mt[tj] = fmaxf(mt[tj], __shfl_xor(mt[tj], 16));
      mt[tj] = fmaxf(mt[tj], __shfl_xor(mt[tj], 32));
      const float mn = fmaxf(m_run[tj], mt[tj]);
      al[tj] = __expf(m_run[tj] - mn);
      m_run[tj] = mn;
    }
    float lt[2] = {0.f, 0.f};
#pragma unroll
    for (int ti = 0; ti < 4; ti++)
#pragma unroll
      for (int tj = 0; tj < 2; tj++) {
        bf16x4 pv;
#pragma unroll
        for (int r = 0; r < 4; r++) {
          const float p = __expf(st[ti][tj][r] - m_run[tj]);
          pv[r] = (bf16_t)p;
          lt[tj] += (float)pv[r];  // denominator consistent with rounded P
        }
        const int q = tj * 16 + l15;
        const int cp2 = (ti * 2 + (quad >> 1)) ^ (q & 7);
        *(bf16x4*)&Ps[wave][q * 64 + cp2 * 8 + (quad & 1) * 4] = pv;
      }
#pragma unroll
    for (int tj = 0; tj < 2; tj++) {
      lt[tj] += __shfl_xor(lt[tj], 16);
      lt[tj] += __shfl_xor(lt[tj], 32);
      l_run[tj] = l_run[tj] * al[tj] + lt[tj];
    }
    // rescale O accumulators (alpha distributed by q=l15, O rows are q=quad*4+r)
#pragma unroll
    for (int ti = 0; ti < 2; ti++) {
      float a0 = __shfl(al[ti], quad * 4 + 0);
      float a1 = __shfl(al[ti], quad * 4 + 1);
      float a2 = __shfl(al[ti], quad * 4 + 2);
      float a3 = __shfl(al[ti], quad * 4 + 3);
#pragma unroll
      for (int dj = 0; dj < 8; dj++) {
        oacc[ti][dj][0] *= a0; oacc[ti][dj][1] *= a1;
        oacc[ti][dj][2] *= a2; oacc[ti][dj][3] *= a3;
      }
    }
    // O += P * V
#pragma unroll
    for (int ks = 0; ks < 2; ks++) {
      bf16x8 pf[2], vf[8];
#pragma unroll
      for (int ti = 0; ti < 2; ti++) {
        const int q = ti * 16 + l15;
        pf[ti] = *(const bf16x8*)&Ps[wave][q * 64 + (((ks * 4 + quad) ^ (q & 7)) * 8)];
      }
#pragma unroll
      for (int dj = 0; dj < 8; dj++) {
        const int d = dj * 16 + l15;
        vf[dj] = *(const bf16x8*)&Vt[d * 64 + (((ks * 4 + quad) ^ (d & 7)) * 8)];
      }
#pragma unroll
      for (int ti = 0; ti < 2; ti++)
#pragma unroll
        for (int dj = 0; dj < 8; dj++)
          oacc[ti][dj] = __builtin_amdgcn_mfma_f32_16x16x32_bf16(pf[ti], vf[dj], oacc[ti][dj], 0, 0, 0);
    }
  }
  // epilogue: (m,l) + normalized partial O for this quarter
  bf16_t* obase; int ostride;
  if (quarter < 2)       { obase = qkvw + 2048 + quarter * 2048; ostride = QKVN; }
  else if (quarter == 2) { obase = oscr2;                        ostride = DIMD; }
  else                   { obase = oscr3;                        ostride = DIMD; }
#pragma unroll
  for (int ti = 0; ti < 2; ti++) {
    if (quad == 0)
      ml[(size_t)quarter * (SEQ * NH) + (size_t)(s0 + wq + ti * 16 + l15) * NH + h] =
          make_float2(m_run[ti], l_run[ti]);
    float li[4];
#pragma unroll
    for (int r = 0; r < 4; r++) li[r] = 1.f / __shfl(l_run[ti], quad * 4 + r);
#pragma unroll
    for (int dj = 0; dj < 8; dj++)
#pragma unroll
      for (int r = 0; r < 4; r++) {
        const float v = oacc[ti][dj][r] * li[r];
        obase[(size_t)(s0 + wq + ti * 16 + quad * 4 + r) * ostride + h * HD + dj * 16 + l15] = (bf16_t)v;
      }
  }
}

// ---------------- merge the four KV quarters ----------------
__global__ __launch_bounds__(256) void combine4(const bf16_t* __restrict__ qkv,
                                                const bf16_t* __restrict__ oscr2,
                                                const float2* __restrict__ ml,
                                                bf16_t* __restrict__ obuf) {
  const int s = blockIdx.x, t = threadIdx.x;
  const int h = t >> 4;  // t*8 elements -> head = t*8/128
  float2 a[4];
#pragma unroll
  for (int q = 0; q < 4; q++) a[q] = ml[(size_t)q * (SEQ * NH) + (size_t)s * NH + h];
  float mstar = fmaxf(fmaxf(a[0].x, a[1].x), fmaxf(a[2].x, a[3].x));
  float wgt[4], tot = 0.f;
#pragma unroll
  for (int q = 0; q < 4; q++) { wgt[q] = __expf(a[q].x - mstar) * a[q].y; tot += wgt[q]; }
  const float inv = 1.f / tot;
#pragma unroll
  for (int q = 0; q < 4; q++) wgt[q] *= inv;
  const bf16x8 o0 = *(const bf16x8*)&qkv[(size_t)s * QKVN + 2048 + t * 8];
  const bf16x8 o1 = *(const bf16x8*)&qkv[(size_t)s * QKVN + 4096 + t * 8];
  const bf16x8 o2 = *(const bf16x8*)&oscr2[(size_t)s * DIMD + t * 8];
  const bf16x8 o3 = *(const bf16x8*)&obuf[(size_t)s * DIMD + t * 8];
  bf16x8 o;
#pragma unroll
  for (int i = 0; i < 8; i++)
    o[i] = (bf16_t)(wgt[0] * (float)o0[i] + wgt[1] * (float)o1[i] +
                    wgt[2] * (float)o2[i] + wgt[3] * (float)o3[i]);
  *(bf16x8*)&obuf[(size_t)s * DIMD + t * 8] = o;
}

// ---------------- launch ----------------
extern "C" void kernel_launch(void* const* d_in, const int* in_sizes, int n_in,
                              void* d_out, int out_size, void* d_ws, size_t ws_size,
                              hipStream_t stream) {
  (void)in_sizes; (void)n_in; (void)out_size;
  const float* x     = (const float*)d_in[0];
  const float* freqs = (const float*)d_in[1];
  const float* Wq    = (const float*)d_in[2];
  const float* bq    = (const float*)d_in[3];
  const float* Wk    = (const float*)d_in[4];
  const float* bk    = (const float*)d_in[5];
  const float* Wv    = (const float*)d_in[6];
  const float* bv    = (const float*)d_in[7];
  const float* Wo    = (const float*)d_in[8];
  const float* bo    = (const float*)d_in[9];
  const float* gq    = (const float*)d_in[10];
  const float* gk    = (const float*)d_in[11];

  // workspace carve (bytes); [0, 37748736) holds xb+Wqkvb during gemm1,
  // reused afterwards for pk / pvt / oscr2.
  char* w = (char*)d_ws;
  bf16_t* xb    = (bf16_t*)(w);                 // x bf16:        12,582,912 B
  bf16_t* Wqkvb = (bf16_t*)(w + 12582912);      // Wq|Wk|Wv bf16: 25,165,824 B
  bf16_t* Wob   = (bf16_t*)(w + 37748736);      // Wo bf16:        8,388,608 B
  bf16_t* qkvb  = (bf16_t*)(w + 46137344);      // qkv bf16:      37,748,736 B
  bf16_t* obuf  = (bf16_t*)(w + 83886080);      // attn out bf16: 12,582,912 B
  float*  bqkv  = (float*) (w + 96468992);      // stacked bias:      24,576 B
  bf16_t* pk    = (bf16_t*)(w);                 // K packed [16][3072][128]: 12,582,912 B
  bf16_t* pvt   = (bf16_t*)(w + 12582912);      // V^T [16][128][3072]:      12,582,912 B
  bf16_t* oscr2 = (bf16_t*)(w + 25165824);      // partial O (q2):           12,582,912 B
  float2* mlbuf = (float2*)(d_out);             // (m,l) [4][3072*16] parked in d_out (1.57 MB),
                                                // fully overwritten by the final GEMM
  if (ws_size < (size_t)96493568) return;

  // converts + bias pack (one launch)
  cvt_all<<<11288, 256, 0, stream>>>(x, Wq, Wk, Wv, Wo, bq, bk, bv, xb, Wqkvb, Wob, bqkv);

  // qkv = x @ [Wq;Wk;Wv]^T + bias   (3072 x 6144 x 2048)
  gemm_nt<true><<<dim3(48, 24), 256, 0, stream>>>(xb, Wqkvb, bqkv, qkvb, SEQ, QKVN, DIMD);
  // RMS(q,k) * g + grid RoPE; q in-place, k -> pk (packed per head)
  rmsrope<<<3072, 256, 0, stream>>>(qkvb, pk, gq, gk, freqs);
  // V transpose -> pvt[h][d][s]
  vtrans<<<dim3(48, NH), 256, 0, stream>>>(qkvb, pvt);
  // attention: q-tile 256, KV-split 4, XCD-stream swizzle
  flash_attn<<<768, 512, 0, stream>>>(qkvb, pk, pvt, qkvb, oscr2, obuf, mlbuf);
  // merge quarters -> obuf
  combine4<<<SEQ, 256, 0, stream>>>(qkvb, oscr2, mlbuf, obuf);
  // out = obuf @ Wo^T + bo  (3072 x 2048 x 2048), fp32 out
  gemm_nt<false><<<dim3(16, 24), 256, 0, stream>>>(obuf, Wob, bo, (float*)d_out, SEQ, DIMD, DIMD);
}

// Round 5
// 421.531 us; speedup vs baseline: 1.5175x; 1.5175x over previous
//
#include <hip/hip_runtime.h>
#include <stdint.h>
#include <stddef.h>

typedef __bf16 bf16_t;
typedef __bf16 bf16x8 __attribute__((ext_vector_type(8)));
typedef __bf16 bf16x4 __attribute__((ext_vector_type(4)));
typedef __bf16 bf16x2 __attribute__((ext_vector_type(2)));
typedef float  f32x4  __attribute__((ext_vector_type(4)));

#define SEQ   3072
#define DIMD  2048
#define NH    16
#define HD    128
#define QKVN  6144

__device__ __forceinline__ void async16(const bf16_t* g, bf16_t* l) {
  __builtin_amdgcn_global_load_lds((const __attribute__((address_space(1))) uint32_t*)g,
                                   (__attribute__((address_space(3))) uint32_t*)l, 16, 0, 0);
}

// ---------------- fused converts + bias pack (one launch) ----------------
__global__ __launch_bounds__(256) void cvt_all(const float* __restrict__ x,
                                               const float* __restrict__ Wq,
                                               const float* __restrict__ Wk,
                                               const float* __restrict__ Wv,
                                               const float* __restrict__ Wo,
                                               const float* __restrict__ bq,
                                               const float* __restrict__ bk,
                                               const float* __restrict__ bv,
                                               bf16_t* __restrict__ xb,
                                               bf16_t* __restrict__ Wqkvb,
                                               bf16_t* __restrict__ Wob,
                                               float* __restrict__ bqkv) {
  const int b = blockIdx.x;
  const float* src; bf16_t* dst; int off;
  if (b < 3072)       { src = x;  dst = xb;              off = b; }
  else if (b < 5120)  { src = Wq; dst = Wqkvb;           off = b - 3072; }
  else if (b < 7168)  { src = Wk; dst = Wqkvb + 4194304; off = b - 5120; }
  else if (b < 9216)  { src = Wv; dst = Wqkvb + 8388608; off = b - 7168; }
  else if (b < 11264) { src = Wo; dst = Wob;             off = b - 9216; }
  else {  // bias pack: 24 blocks cover 6144
    int t = (b - 11264) * 256 + threadIdx.x;
    float v;
    if (t < 2048)      v = bq[t];
    else if (t < 4096) v = bk[t - 2048];
    else               v = bv[t - 4096];
    bqkv[t] = v;
    return;
  }
  const int idx = (off * 256 + threadIdx.x) * 8;
  const float4 a = *(const float4*)(src + idx);
  const float4 c = *(const float4*)(src + idx + 4);
  bf16x8 o;
  o[0] = (bf16_t)a.x; o[1] = (bf16_t)a.y; o[2] = (bf16_t)a.z; o[3] = (bf16_t)a.w;
  o[4] = (bf16_t)c.x; o[5] = (bf16_t)c.y; o[6] = (bf16_t)c.z; o[7] = (bf16_t)c.w;
  *(bf16x8*)(dst + idx) = o;
}

// ---------------- GEMM: C[M,N] = A[M,K] * B[N,K]^T + bias ----------------
template<bool OUT_BF16>
__global__ __launch_bounds__(256, 2) void gemm_nt(const bf16_t* __restrict__ A,
                                                  const bf16_t* __restrict__ B,
                                                  const float* __restrict__ bias,
                                                  void* __restrict__ Cout,
                                                  int M, int N, int K) {
  __shared__ __align__(16) bf16_t As[128 * 64];
  __shared__ __align__(16) bf16_t Bs[128 * 64];
  const int t = threadIdx.x;
  const int lane = t & 63, wave = t >> 6;
  const int quad = lane >> 4, l15 = lane & 15;
  const int wy = wave >> 1, wx = wave & 1;
  const size_t bm = (size_t)blockIdx.y * 128, bn = (size_t)blockIdx.x * 128;
  const bf16_t* Ab = A + bm * K;
  const bf16_t* Bb = B + bn * K;
  f32x4 acc[4][4] = {};
  int srow[4], scol[4];
#pragma unroll
  for (int r = 0; r < 4; r++) {
    int L = r * 256 + t;
    int row = L >> 3, cp = L & 7;
    srow[r] = row;
    scol[r] = (cp ^ (row & 7)) * 8;
  }
  for (int k0 = 0; k0 < K; k0 += 64) {
    __syncthreads();
#pragma unroll
    for (int r = 0; r < 4; r++)
      async16(Ab + (size_t)srow[r] * K + k0 + scol[r], &As[(r * 256 + t) * 8]);
#pragma unroll
    for (int r = 0; r < 4; r++)
      async16(Bb + (size_t)srow[r] * K + k0 + scol[r], &Bs[(r * 256 + t) * 8]);
    __syncthreads();
#pragma unroll
    for (int ks = 0; ks < 2; ks++) {
      bf16x8 af[4], bfv[4];
#pragma unroll
      for (int i = 0; i < 4; i++) {
        int row = wy * 64 + i * 16 + l15;
        af[i] = *(const bf16x8*)&As[row * 64 + (((ks * 4 + quad) ^ (row & 7)) * 8)];
      }
#pragma unroll
      for (int j = 0; j < 4; j++) {
        int row = wx * 64 + j * 16 + l15;
        bfv[j] = *(const bf16x8*)&Bs[row * 64 + (((ks * 4 + quad) ^ (row & 7)) * 8)];
      }
#pragma unroll
      for (int i = 0; i < 4; i++)
#pragma unroll
        for (int j = 0; j < 4; j++)
          acc[i][j] = __builtin_amdgcn_mfma_f32_16x16x32_bf16(af[i], bfv[j], acc[i][j], 0, 0, 0);
    }
  }
#pragma unroll
  for (int i = 0; i < 4; i++) {
#pragma unroll
    for (int j = 0; j < 4; j++) {
      size_t row = bm + wy * 64 + i * 16 + quad * 4;
      size_t col = bn + wx * 64 + j * 16 + l15;
      float bb = bias[col];
#pragma unroll
      for (int r = 0; r < 4; r++) {
        float v = acc[i][j][r] + bb;
        if (OUT_BF16) ((bf16_t*)Cout)[(row + r) * N + col] = (bf16_t)v;
        else          ((float*)Cout)[(row + r) * N + col] = v;
      }
    }
  }
}

// ---------------- RMS + RoPE; q in-place, k packed to pk[h][s][d] ----------------
__global__ __launch_bounds__(256) void rmsrope(bf16_t* __restrict__ qkv,
                                               bf16_t* __restrict__ pk,
                                               const float* __restrict__ gq,
                                               const float* __restrict__ gk,
                                               const float* __restrict__ freqs) {
  const int s = blockIdx.x, t = threadIdx.x;
  bf16_t* row = qkv + (size_t)s * QKVN;
  bf16x8 qv = *(const bf16x8*)&row[t * 8];
  bf16x8 kv = *(const bf16x8*)&row[2048 + t * 8];
  float qf[8], kf[8];
  float qs = 0.f, ks2 = 0.f;
#pragma unroll
  for (int i = 0; i < 8; i++) {
    qf[i] = (float)qv[i]; qs  += qf[i] * qf[i];
    kf[i] = (float)kv[i]; ks2 += kf[i] * kf[i];
  }
#pragma unroll
  for (int m = 1; m < 64; m <<= 1) {
    qs  += __shfl_xor(qs, m);
    ks2 += __shfl_xor(ks2, m);
  }
  __shared__ float red[2][4];
  const int wave = t >> 6, lane = t & 63;
  if (lane == 0) { red[0][wave] = qs; red[1][wave] = ks2; }
  __syncthreads();
  qs  = red[0][0] + red[0][1] + red[0][2] + red[0][3];
  ks2 = red[1][0] + red[1][1] + red[1][2] + red[1][3];
  const float qsc = rsqrtf(qs  / 2048.f + 1e-6f);
  const float ksc = rsqrtf(ks2 / 2048.f + 1e-6f);
  const int sf = s / 384, rem = s - sf * 384;
  const int sh = rem / 24, sw = rem - sh * 24;
  bf16x8 qo, ko;
#pragma unroll
  for (int u = 0; u < 4; u++) {
    const int col = t * 8 + 2 * u;
    const int i = (col >> 1) & 63;                         // pair index within head (c=64)
    const int frow = (i < 22) ? sf : ((i < 43) ? sh : sw); // cf=22, ch=cw=21
    const float ang = freqs[frow * 64 + i];
    float sn, cs;
    __sincosf(ang, &sn, &cs);
    float te = qf[2 * u]     * qsc * gq[col];
    float to = qf[2 * u + 1] * qsc * gq[col + 1];
    qo[2 * u]     = (bf16_t)(te * cs - to * sn);
    qo[2 * u + 1] = (bf16_t)(te * sn + to * cs);
    te = kf[2 * u]     * ksc * gk[col];
    to = kf[2 * u + 1] * ksc * gk[col + 1];
    ko[2 * u]     = (bf16_t)(te * cs - to * sn);
    ko[2 * u + 1] = (bf16_t)(te * sn + to * cs);
  }
  *(bf16x8*)&row[t * 8] = qo;
  // packed K: pk[h][s][d], h = t>>4, d = (t&15)*8
  *(bf16x8*)&pk[((size_t)(t >> 4) * SEQ + s) * HD + (t & 15) * 8] = ko;
}

// ---------------- V transpose: pvt[h][d][s] = qkv[s][4096 + h*128 + d] ----------------
__global__ __launch_bounds__(256) void vtrans(const bf16_t* __restrict__ qkv,
                                              bf16_t* __restrict__ pvt) {
  __shared__ bf16_t tile[128][65];
  const int h = blockIdx.y;
  const int s0 = blockIdx.x * 64;
  const int t = threadIdx.x;
#pragma unroll
  for (int r = 0; r < 4; r++) {
    int L = r * 256 + t, s = L >> 4, cp = L & 15;
    bf16x8 v = *(const bf16x8*)&qkv[(size_t)(s0 + s) * QKVN + 4096 + h * HD + cp * 8];
#pragma unroll
    for (int i = 0; i < 8; i++) tile[cp * 8 + i][s] = v[i];
  }
  __syncthreads();
#pragma unroll
  for (int r = 0; r < 4; r++) {
    int L = r * 256 + t, d = L >> 3, c = L & 7;
    bf16x8 o;
#pragma unroll
    for (int i = 0; i < 8; i++) o[i] = tile[d][c * 8 + i];
    *(bf16x8*)&pvt[((size_t)h * HD + d) * SEQ + s0 + c * 8] = o;
  }
}

// ---------------- Flash attention: R1 grid + double-buffered staging ----------------
// Block = (q-tile 128, head), grid dim3(24,16), 4 waves x 32 q rows (proven R1 shape).
// K from pk[h][s][d], V^T from pvt[h][d][s]; LDS double-buffered, ONE barrier/iter:
// after the barrier, issue async loads for tile kt+1 into buf^1, compute on buf.
__global__ __launch_bounds__(256, 2) void flash_attn(const bf16_t* __restrict__ qkv,
                                                     const bf16_t* __restrict__ pk,
                                                     const bf16_t* __restrict__ pvt,
                                                     bf16_t* __restrict__ ob) {
  __shared__ __align__(16) bf16_t Ks[2][64 * 128];  // [kv][d], 16 chunks/row, xor-swizzled
  __shared__ __align__(16) bf16_t Vt[2][128 * 64];  // [d][kv], 8 chunks/row, xor-swizzled
  __shared__ __align__(16) bf16_t Ps[4][32 * 64];   // per-wave P [q][kv], swizzled
  const int h = blockIdx.y, qt = blockIdx.x;
  const int s0 = qt * 128;
  const int t = threadIdx.x, wave = t >> 6, lane = t & 63;
  const int quad = lane >> 4, l15 = lane & 15;
  const int wq = wave * 32;
  const float scale = 0.08838834764831845f;  // 1/sqrt(128)
  const bf16_t* pkh = pk  + (size_t)h * (SEQ * HD);
  const bf16_t* pvh = pvt + (size_t)h * (HD * SEQ);
  // staging index precompute (per thread: 4 K-chunks + 4 V-chunks)
  int krow4[4], kc4[4], vd4[4], vc4[4];
#pragma unroll
  for (int r = 0; r < 4; r++) {
    int L = r * 256 + t;
    krow4[r] = L >> 4; kc4[r] = (L & 15) ^ (krow4[r] & 7);
    vd4[r]   = L >> 3; vc4[r] = (L & 7)  ^ (vd4[r] & 7);
  }
  bf16x8 qfr[2][4];
#pragma unroll
  for (int tj = 0; tj < 2; tj++)
#pragma unroll
    for (int ks = 0; ks < 4; ks++)
      qfr[tj][ks] = *(const bf16x8*)&qkv[(size_t)(s0 + wq + tj * 16 + l15) * QKVN + h * HD + ks * 32 + quad * 8];
  f32x4 oacc[2][8] = {};
  float m_run[2] = {-3e38f, -3e38f}, l_run[2] = {0.f, 0.f};
  // preload tile 0 into buffer 0
#pragma unroll
  for (int r = 0; r < 4; r++) {
    int L = r * 256 + t;
    async16(pkh + (size_t)krow4[r] * HD + kc4[r] * 8, &Ks[0][L * 8]);
  }
#pragma unroll
  for (int r = 0; r < 4; r++) {
    int L = r * 256 + t;
    async16(pvh + (size_t)vd4[r] * SEQ + vc4[r] * 8, &Vt[0][L * 8]);
  }
  for (int kt = 0; kt < SEQ / 64; kt++) {
    const int cur = kt & 1;
    __syncthreads();  // tile kt landed; all waves done reading buf cur^1
    if (kt + 1 < SEQ / 64) {
      const int kv1 = (kt + 1) * 64;
#pragma unroll
      for (int r = 0; r < 4; r++) {
        int L = r * 256 + t;
        async16(pkh + (size_t)(kv1 + krow4[r]) * HD + kc4[r] * 8, &Ks[cur ^ 1][L * 8]);
      }
#pragma unroll
      for (int r = 0; r < 4; r++) {
        int L = r * 256 + t;
        async16(pvh + (size_t)vd4[r] * SEQ + kv1 + vc4[r] * 8, &Vt[cur ^ 1][L * 8]);
      }
    }
    // S^T = K * Q^T  -> lane holds S^T[kv=ti*16+quad*4+r][q=tj*16+l15]
    f32x4 st[4][2] = {};
#pragma unroll
    for (int ks = 0; ks < 4; ks++) {
      bf16x8 kfr[4];
#pragma unroll
      for (int ti = 0; ti < 4; ti++) {
        const int kr = ti * 16 + l15;
        kfr[ti] = *(const bf16x8*)&Ks[cur][kr * 128 + (((ks * 4 + quad) ^ (kr & 7)) * 8)];
      }
#pragma unroll
      for (int ti = 0; ti < 4; ti++)
#pragma unroll
        for (int tj = 0; tj < 2; tj++)
          st[ti][tj] = __builtin_amdgcn_mfma_f32_16x16x32_bf16(kfr[ti], qfr[tj][ks], st[ti][tj], 0, 0, 0);
    }
    // online softmax over kv (column reduction of S^T = across quads)
    float mt[2] = {-3e38f, -3e38f};
#pragma unroll
    for (int ti = 0; ti < 4; ti++)
#pragma unroll
      for (int tj = 0; tj < 2; tj++)
#pragma unroll
        for (int r = 0; r < 4; r++) {
          st[ti][tj][r] *= scale;
          mt[tj] = fmaxf(mt[tj], st[ti][tj][r]);
        }
    float al[2];
#pragma unroll
    for (int tj = 0; tj < 2; tj++) {
      mt[tj] = fmaxf(mt[tj], __shfl_xor(mt[tj], 16));
      mt[tj] = fmaxf(mt[tj], __shfl_xor(mt[tj], 32));
      const float mn = fmaxf(m_run[tj], mt[tj]);
      al[tj] = __expf(m_run[tj] - mn);
      m_run[tj] = mn;
    }
    float lt[2] = {0.f, 0.f};
#pragma unroll
    for (int ti = 0; ti < 4; ti++)
#pragma unroll
      for (int tj = 0; tj < 2; tj++) {
        bf16x4 pv;
#pragma unroll
        for (int r = 0; r < 4; r++) {
          const float p = __expf(st[ti][tj][r] - m_run[tj]);
          pv[r] = (bf16_t)p;
          lt[tj] += (float)pv[r];  // denominator consistent with rounded P
        }
        const int q = tj * 16 + l15;
        const int cp2 = (ti * 2 + (quad >> 1)) ^ (q & 7);
        *(bf16x4*)&Ps[wave][q * 64 + cp2 * 8 + (quad & 1) * 4] = pv;
      }
#pragma unroll
    for (int tj = 0; tj < 2; tj++) {
      lt[tj] += __shfl_xor(lt[tj], 16);
      lt[tj] += __shfl_xor(lt[tj], 32);
      l_run[tj] = l_run[tj] * al[tj] + lt[tj];
    }
    // rescale O accumulators (alpha distributed by q=l15, O rows are q=quad*4+r)
#pragma unroll
    for (int ti = 0; ti < 2; ti++) {
      float a0 = __shfl(al[ti], quad * 4 + 0);
      float a1 = __shfl(al[ti], quad * 4 + 1);
      float a2 = __shfl(al[ti], quad * 4 + 2);
      float a3 = __shfl(al[ti], quad * 4 + 3);
#pragma unroll
      for (int dj = 0; dj < 8; dj++) {
        oacc[ti][dj][0] *= a0; oacc[ti][dj][1] *= a1;
        oacc[ti][dj][2] *= a2; oacc[ti][dj][3] *= a3;
      }
    }
    // O += P * V
#pragma unroll
    for (int ks = 0; ks < 2; ks++) {
      bf16x8 pf[2], vf[8];
#pragma unroll
      for (int ti = 0; ti < 2; ti++) {
        const int q = ti * 16 + l15;
        pf[ti] = *(const bf16x8*)&Ps[wave][q * 64 + (((ks * 4 + quad) ^ (q & 7)) * 8)];
      }
#pragma unroll
      for (int dj = 0; dj < 8; dj++) {
        const int d = dj * 16 + l15;
        vf[dj] = *(const bf16x8*)&Vt[cur][d * 64 + (((ks * 4 + quad) ^ (d & 7)) * 8)];
      }
#pragma unroll
      for (int ti = 0; ti < 2; ti++)
#pragma unroll
        for (int dj = 0; dj < 8; dj++)
          oacc[ti][dj] = __builtin_amdgcn_mfma_f32_16x16x32_bf16(pf[ti], vf[dj], oacc[ti][dj], 0, 0, 0);
    }
  }
  // epilogue: divide by l, store bf16 into ob [s][n*d]
#pragma unroll
  for (int ti = 0; ti < 2; ti++) {
    float li[4];
#pragma unroll
    for (int r = 0; r < 4; r++) li[r] = 1.f / __shfl(l_run[ti], quad * 4 + r);
#pragma unroll
    for (int dj = 0; dj < 8; dj++)
#pragma unroll
      for (int r = 0; r < 4; r++) {
        const float v = oacc[ti][dj][r] * li[r];
        ob[(size_t)(s0 + wq + ti * 16 + quad * 4 + r) * DIMD + h * HD + dj * 16 + l15] = (bf16_t)v;
      }
  }
}

// ---------------- launch ----------------
extern "C" void kernel_launch(void* const* d_in, const int* in_sizes, int n_in,
                              void* d_out, int out_size, void* d_ws, size_t ws_size,
                              hipStream_t stream) {
  (void)in_sizes; (void)n_in; (void)out_size;
  const float* x     = (const float*)d_in[0];
  const float* freqs = (const float*)d_in[1];
  const float* Wq    = (const float*)d_in[2];
  const float* bq    = (const float*)d_in[3];
  const float* Wk    = (const float*)d_in[4];
  const float* bk    = (const float*)d_in[5];
  const float* Wv    = (const float*)d_in[6];
  const float* bv    = (const float*)d_in[7];
  const float* Wo    = (const float*)d_in[8];
  const float* bo    = (const float*)d_in[9];
  const float* gq    = (const float*)d_in[10];
  const float* gk    = (const float*)d_in[11];

  // workspace carve (bytes); [0, 37748736) holds xb+Wqkvb during gemm1,
  // reused afterwards for pk / pvt.
  char* w = (char*)d_ws;
  bf16_t* xb    = (bf16_t*)(w);                 // x bf16:        12,582,912 B
  bf16_t* Wqkvb = (bf16_t*)(w + 12582912);      // Wq|Wk|Wv bf16: 25,165,824 B
  bf16_t* Wob   = (bf16_t*)(w + 37748736);      // Wo bf16:        8,388,608 B
  bf16_t* qkvb  = (bf16_t*)(w + 46137344);      // qkv bf16:      37,748,736 B
  bf16_t* obuf  = (bf16_t*)(w + 83886080);      // attn out bf16: 12,582,912 B
  float*  bqkv  = (float*) (w + 96468992);      // stacked bias:      24,576 B
  bf16_t* pk    = (bf16_t*)(w);                 // K packed [16][3072][128]: 12,582,912 B
  bf16_t* pvt   = (bf16_t*)(w + 12582912);      // V^T [16][128][3072]:      12,582,912 B
  if (ws_size < (size_t)96493568) return;

  // converts + bias pack (one launch)
  cvt_all<<<11288, 256, 0, stream>>>(x, Wq, Wk, Wv, Wo, bq, bk, bv, xb, Wqkvb, Wob, bqkv);

  // qkv = x @ [Wq;Wk;Wv]^T + bias   (3072 x 6144 x 2048)
  gemm_nt<true><<<dim3(48, 24), 256, 0, stream>>>(xb, Wqkvb, bqkv, qkvb, SEQ, QKVN, DIMD);
  // RMS(q,k) * g + grid RoPE; q in-place, k -> pk (packed per head)
  rmsrope<<<3072, 256, 0, stream>>>(qkvb, pk, gq, gk, freqs);
  // V transpose -> pvt[h][d][s]
  vtrans<<<dim3(48, NH), 256, 0, stream>>>(qkvb, pvt);
  // attention (R1 grid, double-buffered staging) -> obuf
  flash_attn<<<dim3(24, NH), 256, 0, stream>>>(qkvb, pk, pvt, obuf);
  // out = obuf @ Wo^T + bo  (3072 x 2048 x 2048), fp32 out
  gemm_nt<false><<<dim3(16, 24), 256, 0, stream>>>(obuf, Wob, bo, (float*)d_out, SEQ, DIMD, DIMD);
}